// Round 11
// baseline (169.772 us; speedup 1.0000x reference)
//
#include <hip/hip_runtime.h>
#include <hip/hip_bf16.h>
#include <math.h>

using bf16 = __hip_bfloat16;
typedef __attribute__((ext_vector_type(8))) short bf16x8;
typedef __attribute__((ext_vector_type(4))) float f32x4;
typedef __attribute__((ext_vector_type(4))) unsigned short us4;

#define GAS __attribute__((address_space(1)))
#define LAS __attribute__((address_space(3)))

__device__ __forceinline__ void gload_lds16(const bf16* g, bf16* lds) {
  __builtin_amdgcn_global_load_lds((const GAS void*)g, (LAS void*)lds, 16, 0, 0);
}
__device__ __forceinline__ float b2f(unsigned short u) {
  union { unsigned short s; bf16 b; } x; x.s = u; return __bfloat162float(x.b);
}

// ---------------- compaction (atomic-free, stable => deterministic) ----------------
__global__ __launch_bounds__(256) void hist_k(const int* __restrict__ lab,
                                              int* __restrict__ blockHist) {
  const int blk = blockIdx.x, t = threadIdx.x;
  const int lane = t & 63, w = t >> 6;
  const int d = lab[blk * 256 + t];
  __shared__ int wc[4][3];
#pragma unroll
  for (int dd = 0; dd < 3; ++dd) {
    unsigned long long m = __ballot(d == dd);
    if (lane == 0) wc[w][dd] = __popcll(m);
  }
  __syncthreads();
  if (t < 3) blockHist[blk * 3 + t] = wc[0][t] + wc[1][t] + wc[2][t] + wc[3][t];
}

__global__ __launch_bounds__(256) void scan_k(const int* __restrict__ blockHist,
                                              int* __restrict__ blockOff,
                                              int* __restrict__ meta) {
  __shared__ int h[64][3];
  __shared__ int tot[3];
  const int t = threadIdx.x;
  if (t < 192) h[t / 3][t % 3] = blockHist[t];
  __syncthreads();
  if (t < 3) {
    int s = 0;
    for (int b = 0; b < 64; ++b) { int v = h[b][t]; h[b][t] = s; s += v; }
    tot[t] = s;
    meta[t] = s;
  }
  __syncthreads();
  if (t == 0) { meta[4] = 0; meta[5] = tot[0]; meta[6] = tot[0] + tot[1]; }
  if (t < 192) {
    int b = t / 3, d = t % 3;
    int base = (d == 0) ? 0 : (d == 1 ? tot[0] : tot[0] + tot[1]);
    blockOff[t] = base + h[b][d];
  }
}

// writes perm (rank->orig) AND iperm (orig->rank)
__global__ __launch_bounds__(256) void scatter2_k(const int* __restrict__ lab,
                                                  const int* __restrict__ blockOff,
                                                  int* __restrict__ perm,
                                                  int* __restrict__ iperm) {
  const int blk = blockIdx.x, t = threadIdx.x;
  const int lane = t & 63, w = t >> 6;
  const int i = blk * 256 + t;
  const int d = lab[i];
  __shared__ int wc[4][3];
  unsigned long long mymask = 0;
#pragma unroll
  for (int dd = 0; dd < 3; ++dd) {
    unsigned long long m = __ballot(d == dd);
    if (lane == 0) wc[w][dd] = __popcll(m);
    if (dd == d) mymask = m;
  }
  __syncthreads();
  int woff = 0;
  for (int ww = 0; ww < w; ++ww) woff += wc[ww][d];
  const unsigned long long lt = ((unsigned long long)1 << lane) - 1;
  const int rank = blockOff[blk * 3 + d] + woff + __popcll(mymask & lt);
  perm[rank] = i;
  iperm[i] = rank;
}

// -- merged conversions (grid-stride): x -> Xbc (COMPACTED rows) | W1^T | W2^T | text --
__global__ __launch_bounds__(256) void cvt_all_k(const float* __restrict__ x,
                                                 const float* __restrict__ W1,
                                                 const float* __restrict__ W2,
                                                 const float* __restrict__ txt,
                                                 const int* __restrict__ iperm,
                                                 bf16* __restrict__ Xbc,
                                                 bf16* __restrict__ W1T,
                                                 bf16* __restrict__ W2T,
                                                 bf16* __restrict__ Tb) {
  const int nx = 16384 * 1024 / 4;
  const int n1 = 3 * 256 * 1024;
  const int n2 = n1 + 3 * 1024 * 256;
  const int n3 = n2 + 1536 * 1024;
  const int total = nx + n3;
  for (int i = blockIdx.x * 256 + threadIdx.x; i < total; i += 4096 * 256) {
    if (i < nx) {
      const int row = i >> 8, c4 = i & 255;    // 256 float4-chunks per row
      float4 v = ((const float4*)x)[i];
      bf16 t[4] = {__float2bfloat16(v.x), __float2bfloat16(v.y),
                   __float2bfloat16(v.z), __float2bfloat16(v.w)};
      ((us4*)Xbc)[(size_t)iperm[row] * 256 + c4] = *(const us4*)t;   // 1KB/row contiguous
      continue;
    }
    int j = i - nx;
    if (j < n1) {
      int d = j >> 18, rem = j & 262143;
      int r = rem >> 10, k = rem & 1023;
      W1T[j] = __float2bfloat16(W1[(size_t)d * 262144 + (size_t)k * 256 + r]);
    } else if (j < n2) {
      int jj = j - n1;
      int d = jj >> 18, rem = jj & 262143;
      int n = rem >> 8, k = rem & 255;
      W2T[jj] = __float2bfloat16(W2[(size_t)d * 262144 + (size_t)k * 1024 + n]);
    } else {
      int jj = j - n2;
      Tb[jj] = (jj < 1380 * 1024) ? __float2bfloat16(txt[jj]) : __float2bfloat16(0.f);
    }
  }
}

// -------- 128^2 2-phase GEMM for GEMM1/GEMM2 — fully DENSE (compacted rows) --------
// Flat grid, XCD-interleaved: xcd=bid&7, n=seq%NBLK, dm=xcd+8*(seq/NBLK), d=dm>>7, m=dm&127.
// EPI=0: C=relu(acc)->bf16 dense (GEMM1).  EPI=1: g=0.2*relu(acc)+0.8*Xbc (dense),
// dense Fbc write, ssp[n][compact_row] (one writer => deterministic).
template <int EPI, int NBLK>
__global__ __launch_bounds__(256) void gemm_bt(
    const bf16* __restrict__ A, const bf16* __restrict__ BT, bf16* __restrict__ Cv,
    const int* __restrict__ meta, int N, int K, int ldc, int Nvalid,
    const bf16* __restrict__ xb, float* __restrict__ ssp) {
  const int bid = blockIdx.x;
  const int xcd = bid & 7;
  const int seq = bid >> 3;
  const int nblkidx = seq % NBLK;
  const int dm = xcd + 8 * (seq / NBLK);
  const int dom = dm >> 7;
  const int mblk = dm & 127;

  const int cnt = meta[dom];
  const int base = meta[4 + dom];
  BT += (size_t)dom * N * K;

  const int m0 = mblk * 128;
  if (m0 >= cnt) return;
  const int n0 = nblkidx * 128;

  __shared__ bf16 sA[2][128][32];
  __shared__ bf16 sB[2][128][32];

  const int tid = threadIdx.x;
  const int wid = tid >> 6;
  const int lane = tid & 63;

  const int srow = (wid << 4) + (lane >> 2);
  const int skoff = (((lane & 3) ^ ((lane >> 2) & 3)) << 3);

  int p0 = m0 + srow;       if (p0 > cnt - 1) p0 = cnt - 1;
  int p1 = m0 + srow + 64;  if (p1 > cnt - 1) p1 = cnt - 1;
  const bf16* a0 = A + (size_t)(base + p0) * K + skoff;
  const bf16* a1 = A + (size_t)(base + p1) * K + skoff;
  const bf16* b0 = BT + (size_t)(n0 + srow) * K + skoff;
  const bf16* b1 = BT + (size_t)(n0 + srow + 64) * K + skoff;

  const int fr = lane & 15;
  const int fq = lane >> 4;
  const int rchunk = (fq ^ (fr & 3)) << 3;

  f32x4 acc[4][4];
#pragma unroll
  for (int m = 0; m < 4; ++m)
#pragma unroll
    for (int n = 0; n < 4; ++n) acc[m][n] = (f32x4){0.f, 0.f, 0.f, 0.f};

  const int nk = K >> 5;
  auto stage = [&](int buf, int kt) {
    gload_lds16(a0 + kt * 32, &sA[buf][wid * 16][0]);
    gload_lds16(a1 + kt * 32, &sA[buf][wid * 16 + 64][0]);
    gload_lds16(b0 + kt * 32, &sB[buf][wid * 16][0]);
    gload_lds16(b1 + kt * 32, &sB[buf][wid * 16 + 64][0]);
  };

  stage(0, 0);
  __syncthreads();
  const int wr = wid >> 1, wc = wid & 1;
  for (int kt = 0; kt < nk; ++kt) {
    const int cur = kt & 1;
    if (kt + 1 < nk) stage(cur ^ 1, kt + 1);
    bf16x8 af[4], bfr[4];
#pragma unroll
    for (int m = 0; m < 4; ++m)
      af[m] = *(const bf16x8*)&sA[cur][wr * 64 + m * 16 + fr][rchunk];
#pragma unroll
    for (int n = 0; n < 4; ++n)
      bfr[n] = *(const bf16x8*)&sB[cur][wc * 64 + n * 16 + fr][rchunk];
#pragma unroll
    for (int m = 0; m < 4; ++m)
#pragma unroll
      for (int n = 0; n < 4; ++n)
        acc[m][n] = __builtin_amdgcn_mfma_f32_16x16x32_bf16(af[m], bfr[n], acc[m][n], 0, 0, 0);
    __syncthreads();
  }

  if (EPI == 0) {
#pragma unroll
    for (int m = 0; m < 4; ++m) {
#pragma unroll
      for (int r = 0; r < 4; ++r) {
        const int p = m0 + wr * 64 + m * 16 + fq * 4 + r;
        if (p < cnt) {
          const size_t crow = (size_t)(base + p);
#pragma unroll
          for (int n = 0; n < 4; ++n) {
            const int col = n0 + wc * 64 + n * 16 + fr;
            if (col < Nvalid)
              Cv[crow * (size_t)ldc + col] = __float2bfloat16(fmaxf(acc[m][n][r], 0.f));
          }
        }
      }
    }
  } else {
    __shared__ float ssred[128][2];
#pragma unroll
    for (int m = 0; m < 4; ++m) {
#pragma unroll
      for (int r = 0; r < 4; ++r) {
        const int lr = wr * 64 + m * 16 + fq * 4 + r;
        const int p = m0 + lr;
        float rowss = 0.f;
        if (p < cnt) {
          const size_t crow = (size_t)(base + p);
#pragma unroll
          for (int n = 0; n < 4; ++n) {
            const int col = n0 + wc * 64 + n * 16 + fr;
            const float g = 0.2f * fmaxf(acc[m][n][r], 0.f) +
                            0.8f * b2f(*(const unsigned short*)&xb[crow * 1024 + col]);
            Cv[crow * (size_t)ldc + col] = __float2bfloat16(g);
            rowss += g * g;
          }
        }
        rowss += __shfl_xor(rowss, 1, 16);
        rowss += __shfl_xor(rowss, 2, 16);
        rowss += __shfl_xor(rowss, 4, 16);
        rowss += __shfl_xor(rowss, 8, 16);
        if (fr == 0) ssred[lr][wc] = rowss;
      }
    }
    __syncthreads();
    if (tid < 128) {
      const int p = m0 + tid;
      if (p < cnt)
        ssp[(size_t)nblkidx * 16384 + base + p] = ssred[tid][0] + ssred[tid][1];
    }
  }
}

// ============ GEMM3 v3: 128x192, BK=32, 4 waves, 40KB LDS -> 4 blocks/CU ============
// Occupancy route extended (R6/R7 mechanism): 4 independent blocks/CU hide the 2-phase
// barrier drain; grid 1024 = 256 CU x 4 = ONE fully-packed round. __launch_bounds__(256,4)
// pins VGPR <= 128 (acc 96 + a[4] 16 + one b frag live at a time).
// out[perm[row]] = exp(ls) * rinv[row] * (Fbc[row].t[col]); rinv in-kernel from ssp.
__global__ __launch_bounds__(256, 4) void gemm3_v3(
    const bf16* __restrict__ A, const bf16* __restrict__ BT,
    float* __restrict__ C, const float* __restrict__ scale_ptr,
    const float* __restrict__ ssp, const int* __restrict__ perm) {
  extern __shared__ bf16 smem[];
  bf16* sA0 = smem;            // [2][128][32] = 16KB
  bf16* sB0 = smem + 8192;     // [2][192][32] = 24KB

  const int tid = threadIdx.x;
  const int lane = tid & 63, wid = tid >> 6;
  const int wr = wid >> 1, wc = wid & 1;     // 2x2; wave C = 64x96
  const int fr = lane & 15, fq = lane >> 4;

  const int bid = blockIdx.x;
  const int x = bid & 7, seq = bid >> 3;     // seq 0..127
  const int mb = x * 16 + (seq >> 3), nb = seq & 7;
  const int m0 = mb << 7, n0 = nb * 192;

  auto STAGE = [&](int t) {     // A 2 + B 3 loads/thread (BK=32)
    const int s = t & 1, koff = t << 5;
    bf16* da = sA0 + (s << 12);
#pragma unroll
    for (int L = 0; L < 2; ++L) {
      const int idx = (L << 8) + tid;
      const int r = idx >> 2, c = idx & 3;
      gload_lds16(A + (size_t)(m0 + r) * 1024 + koff + ((c ^ (r & 3)) << 3),
                  da + ((idx & ~63) << 3));
    }
    bf16* db = sB0 + s * 6144;
#pragma unroll
    for (int L = 0; L < 3; ++L) {
      const int idx = (L << 8) + tid;
      const int r = idx >> 2, c = idx & 3;
      gload_lds16(BT + (size_t)(n0 + r) * 1024 + koff + ((c ^ (r & 3)) << 3),
                  db + ((idx & ~63) << 3));
    }
  };
  const int rchunk = (fq ^ (fr & 3)) << 3;   // read-side XOR (row&3 == fr&3)

  f32x4 acc[4][6];
#pragma unroll
  for (int m = 0; m < 4; ++m)
#pragma unroll
    for (int n = 0; n < 6; ++n) acc[m][n] = (f32x4){0.f, 0.f, 0.f, 0.f};

  STAGE(0);
  __syncthreads();
  const int nt = 32;
  for (int t = 0; t < nt; ++t) {
    const int s = t & 1;
    if (t + 1 < nt) STAGE(t + 1);
    const bf16* ab = sA0 + (s << 12);
    const bf16* bb = sB0 + s * 6144;
    bf16x8 a[4];
#pragma unroll
    for (int m = 0; m < 4; ++m)
      a[m] = *(const bf16x8*)(ab + (((wr << 6) + (m << 4) + fr) << 5) + rchunk);
#pragma unroll
    for (int n = 0; n < 6; ++n) {
      bf16x8 bf = *(const bf16x8*)(bb + ((wc * 96 + (n << 4) + fr) << 5) + rchunk);
#pragma unroll
      for (int m = 0; m < 4; ++m)
        acc[m][n] = __builtin_amdgcn_mfma_f32_16x16x32_bf16(a[m], bf, acc[m][n], 0, 0, 0);
    }
    __syncthreads();
  }

  // in-kernel rinv + perm for this block's 128 rows
  float* rlds = (float*)smem;                       // 512 B
  int*   plds = (int*)((char*)smem + 512);          // 512 B
  if (tid < 128) {
    float s = 0.f;
#pragma unroll
    for (int b = 0; b < 8; ++b) s += ssp[b * 16384 + m0 + tid];
    rlds[tid] = rsqrtf(s);
    plds[tid] = perm[m0 + tid];
  }
  __syncthreads();

  const float sc = expf(*scale_ptr);
#pragma unroll
  for (int m = 0; m < 4; ++m) {
    const int lrow = (wr << 6) + (m << 4) + (fq << 2);
#pragma unroll
    for (int r = 0; r < 4; ++r) {
      const float rv = sc * rlds[lrow + r];
      const size_t orow = (size_t)plds[lrow + r];
#pragma unroll
      for (int n = 0; n < 6; ++n) {
        const int gcol = n0 + wc * 96 + (n << 4) + fr;
        if (gcol < 1380) C[orow * 1380 + gcol] = acc[m][n][r] * rv;
      }
    }
  }
}

extern "C" void kernel_launch(void* const* d_in, const int* in_sizes, int n_in,
                              void* d_out, int out_size, void* d_ws, size_t ws_size,
                              hipStream_t stream) {
  (void)in_sizes; (void)n_in; (void)out_size; (void)ws_size;
  const float* x    = (const float*)d_in[0];
  const int*   lab  = (const int*)d_in[1];
  const float* W1   = (const float*)d_in[2];
  const float* W2   = (const float*)d_in[3];
  const float* text = (const float*)d_in[4];
  const float* lsc  = (const float*)d_in[5];
  float* out = (float*)d_out;

  const int B = 16384, D = 1024, R = 256, NTP = 1536;

  char* p = (char*)d_ws;
  auto carve = [&](size_t bytes) {
    char* r = p;
    p += (bytes + 255) & ~(size_t)255;
    return r;
  };
  int*   meta  = (int*)carve(64);
  int*   bhist = (int*)carve(64 * 3 * 4);
  int*   boff  = (int*)carve(64 * 3 * 4);
  int*   perm  = (int*)carve((size_t)B * 4);
  int*   iperm = (int*)carve((size_t)B * 4);
  float* ssp   = (float*)carve((size_t)8 * B * 4);
  bf16*  Xbc   = (bf16*)carve((size_t)B * D * 2);
  bf16*  W1T   = (bf16*)carve((size_t)3 * R * D * 2);
  bf16*  W2T   = (bf16*)carve((size_t)3 * D * R * 2);
  bf16*  Tb    = (bf16*)carve((size_t)NTP * D * 2);
  bf16*  H     = (bf16*)carve((size_t)B * R * 2);
  bf16*  Fbc   = (bf16*)carve((size_t)B * D * 2);

  hist_k<<<B / 256, 256, 0, stream>>>(lab, bhist);
  scan_k<<<1, 256, 0, stream>>>(bhist, boff, meta);
  scatter2_k<<<B / 256, 256, 0, stream>>>(lab, boff, perm, iperm);

  cvt_all_k<<<4096, 256, 0, stream>>>(x, W1, W2, text, iperm, Xbc, W1T, W2T, Tb);

  // GEMM1: H = relu(Xbc @ W1T[dom]^T), dense — 8 xcd x 48 dm x 2 n = 768
  gemm_bt<0, 2><<<768, 256, 0, stream>>>(
      Xbc, W1T, H, meta, R, D, R, R, nullptr, nullptr);
  // GEMM2: Fbc = 0.2*relu(H @ W2T^T) + 0.8*Xbc, dense; ssp partials — 3072
  gemm_bt<1, 8><<<3072, 256, 0, stream>>>(
      H, W2T, Fbc, meta, D, R, D, D, Xbc, ssp);
  // GEMM3: out[perm[row]] = exp(ls) * rinv[row] * (Fbc @ Tb^T) — 4 blocks/CU, 1 round
  gemm3_v3<<<1024, 256, 40960, stream>>>(Fbc, Tb, out, lsc, ssp, perm);
}